// Round 1
// baseline (310.360 us; speedup 1.0000x reference)
//
#include <hip/hip_runtime.h>
#include <hip/hip_bf16.h>

// Problem constants
#define BB   4
#define CC   64
#define SS   8
#define NN   (32*64*64)   // 131072
#define NH_  4
#define HD_  16
#define TN   128          // n-tile for stage-1 kernel
#define BPB  128          // blocks per batch in stage-1 kernel

// ---------------------------------------------------------------------------
// Kernel A: stage-1 pass over x.
// For each (b,n): xnorm, sim_s = <slots_norm_s, x/||x||>, e_s = exp(sim_s)
// Accumulate per-block partials: U[s][c] = sum_n x[c,n]*e_s[n], L[s] = sum_n e_s[n]
// sim in [-1,1] -> exp never overflows; max-subtraction of softmax dropped.
// ---------------------------------------------------------------------------
__global__ __launch_bounds__(256) void k_slots_attn(
    const float* __restrict__ x, const float* __restrict__ slot_init,
    float* __restrict__ U_part, float* __restrict__ sume_part)
{
    __shared__ float xt[TN][65];       // [n'][c], padded
    __shared__ float et[SS][TN + 2];   // [s][n']
    __shared__ float sn[CC][SS];       // normalized slots
    __shared__ float snorm[SS];

    const int tid = threadIdx.x;
    const int b   = blockIdx.x / BPB;
    const int blk = blockIdx.x % BPB;

    // normalized slot vectors (same for all b: slot_init is (1,C,S))
    if (tid < SS) {
        float ss = 0.f;
        for (int c = 0; c < CC; ++c) { float v = slot_init[c*SS + tid]; ss += v*v; }
        snorm[tid] = fmaxf(sqrtf(ss), 1e-12f);
    }
    __syncthreads();
    if (tid < CC) {
        for (int s = 0; s < SS; ++s) sn[tid][s] = slot_init[tid*SS + s] / snorm[s];
    }
    __syncthreads();

    const int s_own = tid >> 5;        // 0..7
    const int c_own = tid & 31;        // 0..31
    float acc0 = 0.f, acc1 = 0.f, accS = 0.f;

    const float* xb = x + (size_t)b * CC * NN;
    const int ntiles = NN / TN;        // 1024

    for (int t = blk; t < ntiles; t += BPB) {
        const int n0 = t * TN;
        // load x tile: [c][n'] global -> [n'][c] LDS (padded row 65)
        for (int idx = tid; idx < CC * TN; idx += 256) {
            int c  = idx >> 7;         // TN = 128
            int np = idx & (TN - 1);
            xt[np][c] = xb[(size_t)c * NN + n0 + np];
        }
        __syncthreads();

        // per-n': norm + 8 slot dots + exp
        if (tid < TN) {
            float ss = 0.f;
            float a[SS];
            #pragma unroll
            for (int s = 0; s < SS; ++s) a[s] = 0.f;
            for (int c = 0; c < CC; ++c) {
                float xv = xt[tid][c];
                ss += xv * xv;
                #pragma unroll
                for (int s = 0; s < SS; ++s) a[s] += sn[c][s] * xv;
            }
            float invn = 1.f / fmaxf(sqrtf(ss), 1e-12f);
            #pragma unroll
            for (int s = 0; s < SS; ++s) et[s][tid] = __expf(a[s] * invn);
        }
        __syncthreads();

        // accumulate U[s][c] partials: thread owns (s_own, c_own) and (s_own, c_own+32)
        {
            const float* er = &et[s_own][0];
            for (int np = 0; np < TN; ++np) {
                float e = er[np];
                acc0 += e * xt[np][c_own];
                acc1 += e * xt[np][c_own + 32];
                accS += e;
            }
        }
        __syncthreads();
    }

    size_t base = (((size_t)b * BPB + blk) * SS + s_own) * CC;
    U_part[base + c_own]      = acc0;
    U_part[base + c_own + 32] = acc1;
    if (c_own == 0)
        sume_part[((size_t)b * BPB + blk) * SS + s_own] = accS;
}

// ---------------------------------------------------------------------------
// Kernel R: reduce partials across BPB blocks -> U[b,s,c], L[b,s]
// ---------------------------------------------------------------------------
__global__ __launch_bounds__(256) void k_reduce(
    const float* __restrict__ U_part, const float* __restrict__ sume_part,
    float* __restrict__ Ured, float* __restrict__ Lred)
{
    int gid = blockIdx.x * 256 + threadIdx.x;
    if (gid < BB*SS*CC) {
        int b = gid >> 9, s = (gid >> 6) & 7, c = gid & 63;
        const float* p = U_part + (((size_t)b * BPB) * SS + s) * CC + c;
        float acc = 0.f;
        for (int k = 0; k < BPB; ++k) acc += p[(size_t)k * (SS*CC)];
        Ured[gid] = acc;
    } else if (gid < BB*SS*CC + BB*SS) {
        int t = gid - BB*SS*CC;
        int b = t >> 3, s = t & 7;
        const float* p = sume_part + (size_t)b * BPB * SS + s;
        float acc = 0.f;
        for (int k = 0; k < BPB; ++k) acc += p[k * SS];
        Lred[t] = acc;
    }
}

// ---------------------------------------------------------------------------
// Kernel B: tiny slot pipeline (one block).
// updates = U/L; slot_proj; LN; MHSA over S=8; out_proj + residual; s2f.
// Writes slots_t (st_out) and slots_feat (sf_out).
// ---------------------------------------------------------------------------
__global__ __launch_bounds__(256) void k_slots_small(
    const float* __restrict__ Ured, const float* __restrict__ Lred,
    const float* __restrict__ spw, const float* __restrict__ spb,
    const float* __restrict__ lng, const float* __restrict__ lnb,
    const float* __restrict__ ipw, const float* __restrict__ ipb,
    const float* __restrict__ opw, const float* __restrict__ opb,
    const float* __restrict__ s2fw, const float* __restrict__ s2fb,
    float* __restrict__ st_out, float* __restrict__ sf_out)
{
    __shared__ float upd[BB*SS*CC];     // 8 KB
    __shared__ float st [BB*SS*CC];     // 8 KB
    __shared__ float snb[BB*SS*CC];     // 8 KB
    __shared__ float qkvs[BB*SS*3*CC];  // 24 KB
    __shared__ float ot [BB*SS*CC];     // 8 KB
    const int tid = threadIdx.x;

    for (int i = tid; i < BB*SS*CC; i += 256)
        upd[i] = Ured[i] / Lred[i >> 6];
    __syncthreads();

    // slot_proj: st = upd @ spw^T + spb
    for (int i = tid; i < BB*SS*CC; i += 256) {
        int bs = i >> 6, c = i & 63;
        const float* u = &upd[bs * CC];
        float acc = spb[c];
        for (int cp = 0; cp < CC; ++cp) acc += u[cp] * spw[c*CC + cp];
        st[i] = acc;
    }
    __syncthreads();

    // LayerNorm over channels
    if (tid < BB*SS) {
        const float* p = &st[tid * CC];
        float mu = 0.f;
        for (int c = 0; c < CC; ++c) mu += p[c];
        mu *= (1.f / CC);
        float var = 0.f;
        for (int c = 0; c < CC; ++c) { float d = p[c] - mu; var += d*d; }
        var *= (1.f / CC);
        float r = rsqrtf(var + 1e-5f);
        for (int c = 0; c < CC; ++c)
            snb[tid*CC + c] = (p[c] - mu) * r * lng[c] + lnb[c];
    }
    __syncthreads();

    // qkv = sn @ in_proj_w^T + in_proj_b   (j in [0,192))
    for (int i = tid; i < BB*SS*3*CC; i += 256) {
        int bs = i / (3*CC), j = i % (3*CC);
        const float* p = &snb[bs * CC];
        float acc = ipb[j];
        for (int c = 0; c < CC; ++c) acc += p[c] * ipw[j*CC + c];
        qkvs[i] = acc;
    }
    __syncthreads();

    // MHSA: one thread per (b, head)
    if (tid < BB*NH_) {
        int b = tid >> 2, h = tid & 3;
        const float* qb = &qkvs[b * SS * 3*CC];
        for (int q = 0; q < SS; ++q) {
            float srow[SS];
            float m = -1e30f;
            for (int k = 0; k < SS; ++k) {
                float acc = 0.f;
                for (int d = 0; d < HD_; ++d)
                    acc += qb[q*3*CC + h*HD_ + d] * qb[k*3*CC + CC + h*HD_ + d];
                srow[k] = acc * 0.25f;   // 1/sqrt(16)
                m = fmaxf(m, srow[k]);
            }
            float l = 0.f;
            for (int k = 0; k < SS; ++k) { srow[k] = __expf(srow[k] - m); l += srow[k]; }
            float inv = 1.f / l;
            for (int d = 0; d < HD_; ++d) {
                float acc = 0.f;
                for (int k = 0; k < SS; ++k)
                    acc += srow[k] * qb[k*3*CC + 2*CC + h*HD_ + d];
                ot[(b*SS + q)*CC + h*HD_ + d] = acc * inv;
            }
        }
    }
    __syncthreads();

    // out_proj + residual
    for (int i = tid; i < BB*SS*CC; i += 256) {
        int bs = i >> 6, c = i & 63;
        const float* p = &ot[bs * CC];
        float acc = opb[c];
        for (int cp = 0; cp < CC; ++cp) acc += p[cp] * opw[c*CC + cp];
        st[i] += acc;
    }
    __syncthreads();

    // slots_feat = st @ s2f_w^T + s2f_b ; emit st and sf
    for (int i = tid; i < BB*SS*CC; i += 256) {
        int bs = i >> 6, c = i & 63;
        const float* p = &st[bs * CC];
        float acc = s2fb[c];
        for (int cp = 0; cp < CC; ++cp) acc += p[cp] * s2fw[c*CC + cp];
        sf_out[i] = acc;
        st_out[i] = st[i];
    }
}

// ---------------------------------------------------------------------------
// Kernel C: stage-3 fused pass. Per (b,n):
//   f = feat_w @ x_col + feat_b; sim2_s = <sf_s, f>; softmax over s;
//   out_c = sum_s st[s][c]*a2[s] + x_c
// ---------------------------------------------------------------------------
__global__ __launch_bounds__(256) void k_feat(
    const float* __restrict__ x,
    const float* __restrict__ feat_w, const float* __restrict__ feat_b,
    const float* __restrict__ st_g, const float* __restrict__ sf_g,
    float* __restrict__ out)
{
    __shared__ float wsh[CC][CC];      // 16 KB feat_w
    __shared__ float fbs[CC];
    __shared__ float stc[SS][CC];      // slots_t for this b
    __shared__ float sfc[SS][CC];      // slots_feat for this b

    const int tid = threadIdx.x;
    const int b  = blockIdx.x >> 9;               // 512 blocks per batch
    const int n  = ((blockIdx.x & 511) << 8) + tid;

    for (int i = tid; i < CC*CC; i += 256) wsh[i >> 6][i & 63] = feat_w[i];
    if (tid < CC) fbs[tid] = feat_b[tid];
    for (int i = tid; i < SS*CC; i += 256) {
        stc[i >> 6][i & 63] = st_g[b*SS*CC + i];
        sfc[i >> 6][i & 63] = sf_g[b*SS*CC + i];
    }
    __syncthreads();

    const float* xb = x + (size_t)b * CC * NN + n;
    float xc[CC];
    #pragma unroll
    for (int c = 0; c < CC; ++c) xc[c] = xb[(size_t)c * NN];

    // f = W @ xcol + b  (float4 LDS reads, broadcast across lanes)
    float f[CC];
    #pragma unroll
    for (int o = 0; o < CC; ++o) {
        const float4* wr = (const float4*)&wsh[o][0];
        float acc = fbs[o];
        #pragma unroll
        for (int c4 = 0; c4 < CC/4; ++c4) {
            float4 wv = wr[c4];
            acc += wv.x * xc[c4*4+0];
            acc += wv.y * xc[c4*4+1];
            acc += wv.z * xc[c4*4+2];
            acc += wv.w * xc[c4*4+3];
        }
        f[o] = acc;
    }

    // sim2 + softmax over slots
    float e[SS];
    float m = -1e30f;
    #pragma unroll
    for (int s = 0; s < SS; ++s) {
        const float4* sr = (const float4*)&sfc[s][0];
        float acc = 0.f;
        #pragma unroll
        for (int c4 = 0; c4 < CC/4; ++c4) {
            float4 sv = sr[c4];
            acc += sv.x * f[c4*4+0];
            acc += sv.y * f[c4*4+1];
            acc += sv.z * f[c4*4+2];
            acc += sv.w * f[c4*4+3];
        }
        e[s] = acc;
        m = fmaxf(m, acc);
    }
    float l = 0.f;
    #pragma unroll
    for (int s = 0; s < SS; ++s) { e[s] = __expf(e[s] - m); l += e[s]; }
    float inv = 1.f / l;

    // out = st^T @ a2 + x
    float* ob = out + (size_t)b * CC * NN + n;
    #pragma unroll
    for (int c = 0; c < CC; ++c) {
        float acc = 0.f;
        #pragma unroll
        for (int s = 0; s < SS; ++s) acc += stc[s][c] * e[s];
        ob[(size_t)c * NN] = acc * inv + xc[c];
    }
}

// ---------------------------------------------------------------------------
extern "C" void kernel_launch(void* const* d_in, const int* in_sizes, int n_in,
                              void* d_out, int out_size, void* d_ws, size_t ws_size,
                              hipStream_t stream) {
    const float* x         = (const float*)d_in[0];
    const float* slot_init = (const float*)d_in[1];
    const float* spw       = (const float*)d_in[2];
    const float* spb       = (const float*)d_in[3];
    const float* lng       = (const float*)d_in[4];
    const float* lnb       = (const float*)d_in[5];
    const float* ipw       = (const float*)d_in[6];
    const float* ipb       = (const float*)d_in[7];
    const float* opw       = (const float*)d_in[8];
    const float* opb       = (const float*)d_in[9];
    const float* fw        = (const float*)d_in[10];
    const float* fb        = (const float*)d_in[11];
    const float* s2fw      = (const float*)d_in[12];
    const float* s2fb      = (const float*)d_in[13];
    float* out = (float*)d_out;

    // workspace layout (floats)
    float* w         = (float*)d_ws;
    float* U_part    = w;                                   // 4*128*8*64 = 262144
    float* sume_part = w + 262144;                          // 4*128*8    = 4096
    float* Ured      = w + 262144 + 4096;                   // 2048
    float* Lred      = w + 262144 + 4096 + 2048;            // 32
    float* st_out    = w + 262144 + 4096 + 2048 + 32;       // 2048
    float* sf_out    = w + 262144 + 4096 + 2048 + 32 + 2048;// 2048

    k_slots_attn<<<BB * BPB, 256, 0, stream>>>(x, slot_init, U_part, sume_part);
    k_reduce<<<9, 256, 0, stream>>>(U_part, sume_part, Ured, Lred);
    k_slots_small<<<1, 256, 0, stream>>>(Ured, Lred, spw, spb, lng, lnb,
                                         ipw, ipb, opw, opb, s2fw, s2fb,
                                         st_out, sf_out);
    k_feat<<<BB * (NN/256), 256, 0, stream>>>(x, fw, fb, st_out, sf_out, out);
}

// Round 2
// 180.703 us; speedup vs baseline: 1.7175x; 1.7175x over previous
//
#include <hip/hip_runtime.h>
#include <hip/hip_bf16.h>

// Problem constants
#define BB   4
#define CC   64
#define SS   8
#define NN   (32*64*64)   // 131072
#define NH_  4
#define HD_  16
#define TN   256          // n-tile for stage-1 kernel
#define BPB  128          // blocks per batch in stage-1 kernel

// ---------------------------------------------------------------------------
// Kernel A: stage-1 pass over x.
// Per (b,n): e_s = exp(<sn_s, x/||x||>)  (sim in [-1,1] -> drop max-subtract)
// Per-block partials: U[s][c] = sum_n x[c,n]*e_s[n], L[s] = sum_n e_s[n]
// LDS x tile stored [c][np] with 16B-slot XOR swizzle: slot = c*64 + (j^(c&7))
//  -> conflict-free for: staging writes (contiguous per wave), per-column b32
//     reads (64 consecutive dwords ^ const), per-(s,c) b128 accumulate reads
//     (c&7 spans all 8 bank groups).
// ---------------------------------------------------------------------------
__global__ __launch_bounds__(256) void k_slots_attn(
    const float* __restrict__ x, const float* __restrict__ slot_init,
    float* __restrict__ U_part, float* __restrict__ sume_part)
{
    __shared__ float xt[CC * TN];      // 64 KB, swizzled 16B slots
    __shared__ float et[SS * TN];      // 8 KB
    __shared__ float snT[SS * CC];     // 2 KB, [s][c]
    __shared__ float snorm[SS];

    const int tid = threadIdx.x;
    const int b   = blockIdx.x / BPB;
    const int blk = blockIdx.x % BPB;

    // normalized slot vectors (slot_init is (1,C,S) -> same for all b)
    if (tid < SS) {
        float ss = 0.f;
        for (int c = 0; c < CC; ++c) { float v = slot_init[c*SS + tid]; ss += v*v; }
        snorm[tid] = fmaxf(sqrtf(ss), 1e-12f);
    }
    __syncthreads();
    if (tid < CC) {
        for (int s = 0; s < SS; ++s) snT[s*CC + tid] = slot_init[tid*SS + s] / snorm[s];
    }
    __syncthreads();

    const int s_own = tid >> 5;        // 0..7
    const int c0    = tid & 31;        // 0..31
    const int c1    = c0 + 32;
    float acc0 = 0.f, acc1 = 0.f, accS = 0.f;

    const float* xb = x + (size_t)b * CC * NN;
    const int ntiles = NN / TN;        // 512
    const int wrow = tid >> 6;         // wave id 0..3 -> row within group of 4
    const int j    = tid & 63;         // 16B slot within row

    for (int t = blk; t < ntiles; t += BPB) {
        const int n0 = t * TN;

        // ---- stage: global float4 -> swizzled LDS ----
        #pragma unroll
        for (int k = 0; k < 16; ++k) {
            const int c = k*4 + wrow;
            float4 v = *(const float4*)(xb + (size_t)c * NN + n0 + j*4);
            const int slot = c*64 + (j ^ (c & 7));
            *(float4*)(&xt[slot*4]) = v;
        }
        __syncthreads();

        // ---- dots: thread owns column np = tid ----
        {
            float ss = 0.f;
            float a[SS];
            #pragma unroll
            for (int s = 0; s < SS; ++s) a[s] = 0.f;
            #pragma unroll
            for (int c4 = 0; c4 < 16; ++c4) {
                float xv[4];
                #pragma unroll
                for (int jj = 0; jj < 4; ++jj) {
                    const int c = c4*4 + jj;
                    xv[jj] = xt[c*TN + (tid ^ ((c & 7) << 2))];
                    ss += xv[jj] * xv[jj];
                }
                #pragma unroll
                for (int s = 0; s < SS; ++s) {
                    float4 g4 = *(const float4*)(&snT[s*CC + c4*4]);
                    a[s] += g4.x*xv[0] + g4.y*xv[1] + g4.z*xv[2] + g4.w*xv[3];
                }
            }
            const float invn = 1.f / fmaxf(sqrtf(ss), 1e-12f);
            #pragma unroll
            for (int s = 0; s < SS; ++s) et[s*TN + tid] = __expf(a[s] * invn);
        }
        __syncthreads();

        // ---- accumulate: thread owns (s_own, c0) and (s_own, c1) ----
        #pragma unroll 4
        for (int np4 = 0; np4 < TN/4; ++np4) {
            const float4 e4 = *(const float4*)(&et[s_own*TN + np4*4]);
            const float4 xa = *(const float4*)(&xt[(c0*64 + (np4 ^ (c0 & 7))) * 4]);
            const float4 xc = *(const float4*)(&xt[(c1*64 + (np4 ^ (c1 & 7))) * 4]);
            acc0 += e4.x*xa.x + e4.y*xa.y + e4.z*xa.z + e4.w*xa.w;
            acc1 += e4.x*xc.x + e4.y*xc.y + e4.z*xc.z + e4.w*xc.w;
            accS += e4.x + e4.y + e4.z + e4.w;
        }
        __syncthreads();
    }

    size_t base = (((size_t)b * BPB + blk) * SS + s_own) * CC;
    U_part[base + c0] = acc0;
    U_part[base + c1] = acc1;
    if (c0 == 0)
        sume_part[((size_t)b * BPB + blk) * SS + s_own] = accS;
}

// ---------------------------------------------------------------------------
// Kernel R: reduce partials across BPB blocks -> U[b,s,c], L[b,s]
// ---------------------------------------------------------------------------
__global__ __launch_bounds__(256) void k_reduce(
    const float* __restrict__ U_part, const float* __restrict__ sume_part,
    float* __restrict__ Ured, float* __restrict__ Lred)
{
    int gid = blockIdx.x * 256 + threadIdx.x;
    if (gid < BB*SS*CC) {
        int b = gid >> 9, s = (gid >> 6) & 7, c = gid & 63;
        const float* p = U_part + (((size_t)b * BPB) * SS + s) * CC + c;
        float acc = 0.f;
        for (int k = 0; k < BPB; ++k) acc += p[(size_t)k * (SS*CC)];
        Ured[gid] = acc;
    } else if (gid < BB*SS*CC + BB*SS) {
        int t = gid - BB*SS*CC;
        int b = t >> 3, s = t & 7;
        const float* p = sume_part + (size_t)b * BPB * SS + s;
        float acc = 0.f;
        for (int k = 0; k < BPB; ++k) acc += p[k * SS];
        Lred[t] = acc;
    }
}

// ---------------------------------------------------------------------------
// Kernel B: tiny slot pipeline (one block).
// updates = U/L; slot_proj; LN; MHSA over S=8; out_proj + residual;
// sf = st @ s2f_w^T + s2f_b;  g = sf @ feat_w  (i.e. g[bs][c]=sum_o sf[o]*fw[o][c]);
// h = sf . feat_b.  Emits st, g, h.
// ---------------------------------------------------------------------------
__global__ __launch_bounds__(256) void k_slots_small(
    const float* __restrict__ Ured, const float* __restrict__ Lred,
    const float* __restrict__ spw, const float* __restrict__ spb,
    const float* __restrict__ lng, const float* __restrict__ lnb,
    const float* __restrict__ ipw, const float* __restrict__ ipb,
    const float* __restrict__ opw, const float* __restrict__ opb,
    const float* __restrict__ s2fw, const float* __restrict__ s2fb,
    const float* __restrict__ fw,  const float* __restrict__ fb,
    float* __restrict__ st_out, float* __restrict__ g_out, float* __restrict__ h_out)
{
    __shared__ float upd[BB*SS*CC];     // 8 KB
    __shared__ float st [BB*SS*CC];     // 8 KB
    __shared__ float snb[BB*SS*CC];     // 8 KB
    __shared__ float qkvs[BB*SS*3*CC];  // 24 KB
    __shared__ float ot [BB*SS*CC];     // 8 KB
    __shared__ float sfs[BB*SS*CC];     // 8 KB
    const int tid = threadIdx.x;

    for (int i = tid; i < BB*SS*CC; i += 256)
        upd[i] = Ured[i] / Lred[i >> 6];
    __syncthreads();

    // slot_proj: st = upd @ spw^T + spb
    for (int i = tid; i < BB*SS*CC; i += 256) {
        int bs = i >> 6, c = i & 63;
        const float* u = &upd[bs * CC];
        float acc = spb[c];
        for (int cp = 0; cp < CC; ++cp) acc += u[cp] * spw[c*CC + cp];
        st[i] = acc;
    }
    __syncthreads();

    // LayerNorm over channels
    if (tid < BB*SS) {
        const float* p = &st[tid * CC];
        float mu = 0.f;
        for (int c = 0; c < CC; ++c) mu += p[c];
        mu *= (1.f / CC);
        float var = 0.f;
        for (int c = 0; c < CC; ++c) { float d = p[c] - mu; var += d*d; }
        var *= (1.f / CC);
        float r = rsqrtf(var + 1e-5f);
        for (int c = 0; c < CC; ++c)
            snb[tid*CC + c] = (p[c] - mu) * r * lng[c] + lnb[c];
    }
    __syncthreads();

    // qkv = sn @ in_proj_w^T + in_proj_b
    for (int i = tid; i < BB*SS*3*CC; i += 256) {
        int bs = i / (3*CC), jj = i % (3*CC);
        const float* p = &snb[bs * CC];
        float acc = ipb[jj];
        for (int c = 0; c < CC; ++c) acc += p[c] * ipw[jj*CC + c];
        qkvs[i] = acc;
    }
    __syncthreads();

    // MHSA: one thread per (b, head)
    if (tid < BB*NH_) {
        int b = tid >> 2, h = tid & 3;
        const float* qb = &qkvs[b * SS * 3*CC];
        for (int q = 0; q < SS; ++q) {
            float srow[SS];
            float m = -1e30f;
            for (int k = 0; k < SS; ++k) {
                float acc = 0.f;
                for (int d = 0; d < HD_; ++d)
                    acc += qb[q*3*CC + h*HD_ + d] * qb[k*3*CC + CC + h*HD_ + d];
                srow[k] = acc * 0.25f;   // 1/sqrt(16)
                m = fmaxf(m, srow[k]);
            }
            float l = 0.f;
            for (int k = 0; k < SS; ++k) { srow[k] = __expf(srow[k] - m); l += srow[k]; }
            float inv = 1.f / l;
            for (int d = 0; d < HD_; ++d) {
                float acc = 0.f;
                for (int k = 0; k < SS; ++k)
                    acc += srow[k] * qb[k*3*CC + 2*CC + h*HD_ + d];
                ot[(b*SS + q)*CC + h*HD_ + d] = acc * inv;
            }
        }
    }
    __syncthreads();

    // out_proj + residual
    for (int i = tid; i < BB*SS*CC; i += 256) {
        int bs = i >> 6, c = i & 63;
        const float* p = &ot[bs * CC];
        float acc = opb[c];
        for (int cp = 0; cp < CC; ++cp) acc += p[cp] * opw[c*CC + cp];
        st[i] += acc;
    }
    __syncthreads();

    // slots_feat = st @ s2f_w^T + s2f_b
    for (int i = tid; i < BB*SS*CC; i += 256) {
        int bs = i >> 6, c = i & 63;
        const float* p = &st[bs * CC];
        float acc = s2fb[c];
        for (int cp = 0; cp < CC; ++cp) acc += p[cp] * s2fw[c*CC + cp];
        sfs[i] = acc;
        st_out[i] = st[i];
    }
    __syncthreads();

    // g[bs][c] = sum_o sf[bs][o] * fw[o][c];  h[bs] = sum_o sf[bs][o]*fb[o]
    for (int i = tid; i < BB*SS*CC; i += 256) {
        int bs = i >> 6, c = i & 63;
        const float* p = &sfs[bs * CC];
        float acc = 0.f;
        for (int o = 0; o < CC; ++o) acc += p[o] * fw[o*CC + c];
        g_out[i] = acc;
    }
    if (tid < BB*SS) {
        const float* p = &sfs[tid * CC];
        float acc = 0.f;
        for (int o = 0; o < CC; ++o) acc += p[o] * fb[o];
        h_out[tid] = acc;
    }
}

// ---------------------------------------------------------------------------
// Kernel C: stage-3 fused pass. Per (b,n):
//   sim2_s = <g_s, x_col> + h_s; softmax over s; out_c = sum_s st[s][c]*a2[s] + x_c
// x read ONCE into registers; no 64x64 matvec (folded into g).
// ---------------------------------------------------------------------------
__global__ __launch_bounds__(256) void k_feat(
    const float* __restrict__ x,
    const float* __restrict__ st_g, const float* __restrict__ g_g,
    const float* __restrict__ h_g,
    float* __restrict__ out)
{
    __shared__ float stS[SS*CC];       // 2 KB
    __shared__ float gS [SS*CC];       // 2 KB
    __shared__ float hS [SS];

    const int tid = threadIdx.x;
    const int b  = blockIdx.x >> 9;               // 512 blocks per batch
    const int n  = ((blockIdx.x & 511) << 8) + tid;

    for (int i = tid; i < SS*CC; i += 256) {
        stS[i] = st_g[b*SS*CC + i];
        gS[i]  = g_g [b*SS*CC + i];
    }
    if (tid < SS) hS[tid] = h_g[b*SS + tid];
    __syncthreads();

    const float* xb = x + (size_t)b * CC * NN + n;
    float xc[CC];
    #pragma unroll
    for (int c = 0; c < CC; ++c) xc[c] = xb[(size_t)c * NN];

    // sim2 = g . x + h
    float a[SS];
    #pragma unroll
    for (int s = 0; s < SS; ++s) a[s] = hS[s];
    #pragma unroll
    for (int c4 = 0; c4 < CC/4; ++c4) {
        #pragma unroll
        for (int s = 0; s < SS; ++s) {
            float4 g4 = *(const float4*)(&gS[s*CC + c4*4]);
            a[s] += g4.x*xc[c4*4+0] + g4.y*xc[c4*4+1]
                  + g4.z*xc[c4*4+2] + g4.w*xc[c4*4+3];
        }
    }

    // softmax over slots
    float m = a[0];
    #pragma unroll
    for (int s = 1; s < SS; ++s) m = fmaxf(m, a[s]);
    float l = 0.f;
    #pragma unroll
    for (int s = 0; s < SS; ++s) { a[s] = __expf(a[s] - m); l += a[s]; }
    const float inv = 1.f / l;

    // out = st^T @ a2 + x
    float* ob = out + (size_t)b * CC * NN + n;
    #pragma unroll
    for (int c4 = 0; c4 < CC/4; ++c4) {
        float o0 = 0.f, o1 = 0.f, o2 = 0.f, o3 = 0.f;
        #pragma unroll
        for (int s = 0; s < SS; ++s) {
            float4 s4 = *(const float4*)(&stS[s*CC + c4*4]);
            o0 += s4.x * a[s]; o1 += s4.y * a[s];
            o2 += s4.z * a[s]; o3 += s4.w * a[s];
        }
        ob[(size_t)(c4*4+0) * NN] = o0 * inv + xc[c4*4+0];
        ob[(size_t)(c4*4+1) * NN] = o1 * inv + xc[c4*4+1];
        ob[(size_t)(c4*4+2) * NN] = o2 * inv + xc[c4*4+2];
        ob[(size_t)(c4*4+3) * NN] = o3 * inv + xc[c4*4+3];
    }
}

// ---------------------------------------------------------------------------
extern "C" void kernel_launch(void* const* d_in, const int* in_sizes, int n_in,
                              void* d_out, int out_size, void* d_ws, size_t ws_size,
                              hipStream_t stream) {
    const float* x         = (const float*)d_in[0];
    const float* slot_init = (const float*)d_in[1];
    const float* spw       = (const float*)d_in[2];
    const float* spb       = (const float*)d_in[3];
    const float* lng       = (const float*)d_in[4];
    const float* lnb       = (const float*)d_in[5];
    const float* ipw       = (const float*)d_in[6];
    const float* ipb       = (const float*)d_in[7];
    const float* opw       = (const float*)d_in[8];
    const float* opb       = (const float*)d_in[9];
    const float* fw        = (const float*)d_in[10];
    const float* fb        = (const float*)d_in[11];
    const float* s2fw      = (const float*)d_in[12];
    const float* s2fb      = (const float*)d_in[13];
    float* out = (float*)d_out;

    // workspace layout (floats)
    float* w         = (float*)d_ws;
    float* U_part    = w;                       // 4*128*8*64 = 262144
    float* sume_part = w + 262144;              // 4096
    float* Ured      = w + 266240;              // 2048
    float* Lred      = w + 268288;              // 32
    float* st_out    = w + 268320;              // 2048
    float* g_out     = w + 270368;              // 2048
    float* h_out     = w + 272416;              // 32

    k_slots_attn<<<BB * BPB, 256, 0, stream>>>(x, slot_init, U_part, sume_part);
    k_reduce<<<9, 256, 0, stream>>>(U_part, sume_part, Ured, Lred);
    k_slots_small<<<1, 256, 0, stream>>>(Ured, Lred, spw, spb, lng, lnb,
                                         ipw, ipb, opw, opb, s2fw, s2fb,
                                         fw, fb, st_out, g_out, h_out);
    k_feat<<<BB * (NN/256), 256, 0, stream>>>(x, st_out, g_out, h_out, out);
}

// Round 3
// 153.902 us; speedup vs baseline: 2.0166x; 1.1741x over previous
//
#include <hip/hip_runtime.h>
#include <hip/hip_bf16.h>

// Problem constants
#define BB   4
#define CC   64
#define SS   8
#define NN   (32*64*64)   // 131072
#define NH_  4
#define HD_  16
#define TN   256          // n-tile for stage-1 kernel
#define BPB  128          // blocks per batch in stage-1 kernel

// ---------------------------------------------------------------------------
// Kernel A: stage-1 pass over x.
// Per (b,n): e_s = exp(<sn_s, x/||x||>)  (sim in [-1,1] -> drop max-subtract)
// Per-block partials: U[s][c] = sum_n x[c,n]*e_s[n], L[s] = sum_n e_s[n]
// LDS x tile stored [c][np] with 16B-slot XOR swizzle: slot = c*64 + (j^(c&7))
// ---------------------------------------------------------------------------
__global__ __launch_bounds__(256) void k_slots_attn(
    const float* __restrict__ x, const float* __restrict__ slot_init,
    float* __restrict__ U_part, float* __restrict__ sume_part)
{
    __shared__ float xt[CC * TN];      // 64 KB, swizzled 16B slots
    __shared__ float et[SS * TN];      // 8 KB
    __shared__ float snT[SS * CC];     // 2 KB, [s][c]
    __shared__ float snorm[SS];

    const int tid = threadIdx.x;
    const int b   = blockIdx.x / BPB;
    const int blk = blockIdx.x % BPB;

    // normalized slot vectors (slot_init is (1,C,S) -> same for all b)
    if (tid < SS) {
        float ss = 0.f;
        for (int c = 0; c < CC; ++c) { float v = slot_init[c*SS + tid]; ss += v*v; }
        snorm[tid] = fmaxf(sqrtf(ss), 1e-12f);
    }
    __syncthreads();
    if (tid < CC) {
        for (int s = 0; s < SS; ++s) snT[s*CC + tid] = slot_init[tid*SS + s] / snorm[s];
    }
    __syncthreads();

    const int s_own = tid >> 5;        // 0..7
    const int c0    = tid & 31;        // 0..31
    const int c1    = c0 + 32;
    float acc0 = 0.f, acc1 = 0.f, accS = 0.f;

    const float* xb = x + (size_t)b * CC * NN;
    const int ntiles = NN / TN;        // 512
    const int wrow = tid >> 6;         // wave id 0..3
    const int j    = tid & 63;         // 16B slot within row

    for (int t = blk; t < ntiles; t += BPB) {
        const int n0 = t * TN;

        // ---- stage: global float4 -> swizzled LDS ----
        #pragma unroll
        for (int k = 0; k < 16; ++k) {
            const int c = k*4 + wrow;
            float4 v = *(const float4*)(xb + (size_t)c * NN + n0 + j*4);
            const int slot = c*64 + (j ^ (c & 7));
            *(float4*)(&xt[slot*4]) = v;
        }
        __syncthreads();

        // ---- dots: thread owns column np = tid ----
        {
            float ss = 0.f;
            float a[SS];
            #pragma unroll
            for (int s = 0; s < SS; ++s) a[s] = 0.f;
            #pragma unroll
            for (int c4 = 0; c4 < 16; ++c4) {
                float xv[4];
                #pragma unroll
                for (int jj = 0; jj < 4; ++jj) {
                    const int c = c4*4 + jj;
                    xv[jj] = xt[c*TN + (tid ^ ((c & 7) << 2))];
                    ss += xv[jj] * xv[jj];
                }
                #pragma unroll
                for (int s = 0; s < SS; ++s) {
                    float4 g4 = *(const float4*)(&snT[s*CC + c4*4]);
                    a[s] += g4.x*xv[0] + g4.y*xv[1] + g4.z*xv[2] + g4.w*xv[3];
                }
            }
            const float invn = 1.f / fmaxf(sqrtf(ss), 1e-12f);
            #pragma unroll
            for (int s = 0; s < SS; ++s) et[s*TN + tid] = __expf(a[s] * invn);
        }
        __syncthreads();

        // ---- accumulate: thread owns (s_own, c0) and (s_own, c1) ----
        #pragma unroll 4
        for (int np4 = 0; np4 < TN/4; ++np4) {
            const float4 e4 = *(const float4*)(&et[s_own*TN + np4*4]);
            const float4 xa = *(const float4*)(&xt[(c0*64 + (np4 ^ (c0 & 7))) * 4]);
            const float4 xc = *(const float4*)(&xt[(c1*64 + (np4 ^ (c1 & 7))) * 4]);
            acc0 += e4.x*xa.x + e4.y*xa.y + e4.z*xa.z + e4.w*xa.w;
            acc1 += e4.x*xc.x + e4.y*xc.y + e4.z*xc.z + e4.w*xc.w;
            accS += e4.x + e4.y + e4.z + e4.w;
        }
        __syncthreads();
    }

    size_t base = (((size_t)b * BPB + blk) * SS + s_own) * CC;
    U_part[base + c0] = acc0;
    U_part[base + c1] = acc1;
    if (c0 == 0)
        sume_part[((size_t)b * BPB + blk) * SS + s_own] = accS;
}

// ---------------------------------------------------------------------------
// Kernel B: tiny slot pipeline (one block), now fully parallel + merged reduce.
// Thread layout for matvecs: c = tid&63 owns weight ROW c in registers
// (16 independent float4 global loads); quad = tid>>6 owns batch b=quad's 8
// (b,s) rows; inputs read as LDS b128 BROADCASTs. MHSA: 128 threads, one per
// (b,h,q). LN: 8 threads/row + shfl_xor.
// ---------------------------------------------------------------------------
__global__ __launch_bounds__(256) void k_slots_small(
    const float* __restrict__ U_part, const float* __restrict__ sume_part,
    const float* __restrict__ spw, const float* __restrict__ spb,
    const float* __restrict__ lng, const float* __restrict__ lnb,
    const float* __restrict__ ipw, const float* __restrict__ ipb,
    const float* __restrict__ opw, const float* __restrict__ opb,
    const float* __restrict__ s2fw, const float* __restrict__ s2fb,
    const float* __restrict__ fw,  const float* __restrict__ fb,
    float* __restrict__ st_out, float* __restrict__ g_out, float* __restrict__ h_out)
{
    __shared__ float upd[BB*SS*CC];     // 8 KB
    __shared__ float st [BB*SS*CC];     // 8 KB
    __shared__ float snb[BB*SS*CC];     // 8 KB
    __shared__ float qkvs[BB*SS*3*CC];  // 24 KB  [bs][192]
    __shared__ float ot [BB*SS*CC];     // 8 KB
    __shared__ float sfs[BB*SS*CC];     // 8 KB
    __shared__ float Ls[BB*SS];

    const int tid  = threadIdx.x;
    const int c    = tid & 63;
    const int quad = tid >> 6;          // = batch b

    // ---- merged reduce: U[b,s,c] over BPB partial blocks ----
    float uacc[SS];
    #pragma unroll
    for (int s = 0; s < SS; ++s) uacc[s] = 0.f;
    for (int k = 0; k < BPB; ++k) {
        const float* p = U_part + ((size_t)(quad*BPB + k) * SS) * CC + c;
        #pragma unroll
        for (int s = 0; s < SS; ++s) uacc[s] += p[s*CC];
    }
    if (tid < BB*SS) {
        int b = tid >> 3, s = tid & 7;
        const float* p = sume_part + (size_t)b*BPB*SS + s;
        float acc = 0.f;
        for (int k = 0; k < BPB; ++k) acc += p[k*SS];
        Ls[tid] = acc;
    }
    __syncthreads();
    #pragma unroll
    for (int s = 0; s < SS; ++s)
        upd[(quad*SS + s)*CC + c] = uacc[s] / Ls[quad*SS + s];
    __syncthreads();

    float wreg[CC];

    // ---- P1: slot_proj  st = upd @ spw^T + spb ----
    #pragma unroll
    for (int i = 0; i < 16; ++i)
        *(float4*)&wreg[i*4] = *(const float4*)(spw + c*CC + i*4);
    {
        const float bias = spb[c];
        #pragma unroll
        for (int r = 0; r < SS; ++r) {
            const int bs = quad*SS + r;
            float acc = bias;
            #pragma unroll
            for (int i = 0; i < 16; ++i) {
                float4 u4 = *(const float4*)&upd[bs*CC + i*4];
                acc += u4.x*wreg[i*4+0] + u4.y*wreg[i*4+1]
                     + u4.z*wreg[i*4+2] + u4.w*wreg[i*4+3];
            }
            st[bs*CC + c] = acc;
        }
    }
    __syncthreads();

    // ---- P2: LayerNorm over channels (8 threads per row) ----
    {
        const int row = tid >> 3;      // 0..31
        const int l8  = tid & 7;
        float v[8];
        *(float4*)&v[0] = *(const float4*)&st[row*CC + l8*8];
        *(float4*)&v[4] = *(const float4*)&st[row*CC + l8*8 + 4];
        float sum = v[0]+v[1]+v[2]+v[3]+v[4]+v[5]+v[6]+v[7];
        sum += __shfl_xor(sum, 1); sum += __shfl_xor(sum, 2); sum += __shfl_xor(sum, 4);
        const float mu = sum * (1.f/64.f);
        float vs = 0.f;
        #pragma unroll
        for (int jj = 0; jj < 8; ++jj) { float d = v[jj]-mu; vs += d*d; }
        vs += __shfl_xor(vs, 1); vs += __shfl_xor(vs, 2); vs += __shfl_xor(vs, 4);
        const float rstd = rsqrtf(vs*(1.f/64.f) + 1e-5f);
        float4 ga = *(const float4*)(lng + l8*8), gb = *(const float4*)(lng + l8*8 + 4);
        float4 ba = *(const float4*)(lnb + l8*8), bb2 = *(const float4*)(lnb + l8*8 + 4);
        const float gv[8]  = {ga.x,ga.y,ga.z,ga.w,gb.x,gb.y,gb.z,gb.w};
        const float bv[8]  = {ba.x,ba.y,ba.z,ba.w,bb2.x,bb2.y,bb2.z,bb2.w};
        #pragma unroll
        for (int jj = 0; jj < 8; ++jj)
            snb[row*CC + l8*8 + jj] = (v[jj]-mu)*rstd*gv[jj] + bv[jj];
    }
    __syncthreads();

    // ---- P3: qkv = snb @ in_proj_w^T + in_proj_b (3 sub-matvecs) ----
    #pragma unroll 1
    for (int m = 0; m < 3; ++m) {
        #pragma unroll
        for (int i = 0; i < 16; ++i)
            *(float4*)&wreg[i*4] = *(const float4*)(ipw + (size_t)(m*CC + c)*CC + i*4);
        const float bias = ipb[m*CC + c];
        #pragma unroll
        for (int r = 0; r < SS; ++r) {
            const int bs = quad*SS + r;
            float acc = bias;
            #pragma unroll
            for (int i = 0; i < 16; ++i) {
                float4 u4 = *(const float4*)&snb[bs*CC + i*4];
                acc += u4.x*wreg[i*4+0] + u4.y*wreg[i*4+1]
                     + u4.z*wreg[i*4+2] + u4.w*wreg[i*4+3];
            }
            qkvs[bs*3*CC + m*CC + c] = acc;
        }
    }
    __syncthreads();

    // ---- P4: MHSA, one thread per (b,h,q) ----
    if (tid < BB*NH_*SS) {
        const int b = tid >> 5, h = (tid >> 3) & 3, q = tid & 7;
        const float* base = &qkvs[b*SS*3*CC];
        float qreg[HD_];
        #pragma unroll
        for (int i = 0; i < 4; ++i)
            *(float4*)&qreg[i*4] = *(const float4*)&base[q*3*CC + h*HD_ + i*4];
        float srow[SS];
        float m = -1e30f;
        #pragma unroll
        for (int k = 0; k < SS; ++k) {
            float kreg[HD_];
            #pragma unroll
            for (int i = 0; i < 4; ++i)
                *(float4*)&kreg[i*4] = *(const float4*)&base[k*3*CC + CC + h*HD_ + i*4];
            float acc = 0.f;
            #pragma unroll
            for (int d = 0; d < HD_; ++d) acc += qreg[d]*kreg[d];
            srow[k] = acc * 0.25f;     // 1/sqrt(16)
            m = fmaxf(m, srow[k]);
        }
        float l = 0.f;
        #pragma unroll
        for (int k = 0; k < SS; ++k) { srow[k] = __expf(srow[k]-m); l += srow[k]; }
        const float inv = 1.f / l;
        float oreg[HD_];
        #pragma unroll
        for (int d = 0; d < HD_; ++d) oreg[d] = 0.f;
        #pragma unroll
        for (int k = 0; k < SS; ++k) {
            float vreg[HD_];
            #pragma unroll
            for (int i = 0; i < 4; ++i)
                *(float4*)&vreg[i*4] = *(const float4*)&base[k*3*CC + 2*CC + h*HD_ + i*4];
            #pragma unroll
            for (int d = 0; d < HD_; ++d) oreg[d] += srow[k]*vreg[d];
        }
        #pragma unroll
        for (int d = 0; d < HD_; ++d)
            ot[(b*SS + q)*CC + h*HD_ + d] = oreg[d] * inv;
    }
    __syncthreads();

    // ---- P5: out_proj + residual into st ----
    #pragma unroll
    for (int i = 0; i < 16; ++i)
        *(float4*)&wreg[i*4] = *(const float4*)(opw + c*CC + i*4);
    {
        const float bias = opb[c];
        #pragma unroll
        for (int r = 0; r < SS; ++r) {
            const int bs = quad*SS + r;
            float acc = bias;
            #pragma unroll
            for (int i = 0; i < 16; ++i) {
                float4 u4 = *(const float4*)&ot[bs*CC + i*4];
                acc += u4.x*wreg[i*4+0] + u4.y*wreg[i*4+1]
                     + u4.z*wreg[i*4+2] + u4.w*wreg[i*4+3];
            }
            st[bs*CC + c] += acc;
        }
    }
    __syncthreads();

    // ---- P6: slots_feat = st @ s2f_w^T + s2f_b ; emit st ----
    #pragma unroll
    for (int i = 0; i < 16; ++i)
        *(float4*)&wreg[i*4] = *(const float4*)(s2fw + c*CC + i*4);
    {
        const float bias = s2fb[c];
        #pragma unroll
        for (int r = 0; r < SS; ++r) {
            const int bs = quad*SS + r;
            float acc = bias;
            #pragma unroll
            for (int i = 0; i < 16; ++i) {
                float4 u4 = *(const float4*)&st[bs*CC + i*4];
                acc += u4.x*wreg[i*4+0] + u4.y*wreg[i*4+1]
                     + u4.z*wreg[i*4+2] + u4.w*wreg[i*4+3];
            }
            sfs[bs*CC + c] = acc;
            st_out[bs*CC + c] = st[bs*CC + c];
        }
    }
    __syncthreads();

    // ---- P7: g[bs][c] = sum_o sfs[bs][o]*fw[o][c];  h[bs] = sfs[bs].fb ----
    #pragma unroll
    for (int o = 0; o < CC; ++o) wreg[o] = fw[o*CC + c];   // coalesced col loads
    #pragma unroll
    for (int r = 0; r < SS; ++r) {
        const int bs = quad*SS + r;
        float acc = 0.f;
        #pragma unroll
        for (int i = 0; i < 16; ++i) {
            float4 u4 = *(const float4*)&sfs[bs*CC + i*4];
            acc += u4.x*wreg[i*4+0] + u4.y*wreg[i*4+1]
                 + u4.z*wreg[i*4+2] + u4.w*wreg[i*4+3];
        }
        g_out[bs*CC + c] = acc;
    }
    if (tid < BB*SS) {
        const float* p = &sfs[tid * CC];
        float acc = 0.f;
        for (int o = 0; o < CC; ++o) acc += p[o] * fb[o];
        h_out[tid] = acc;
    }
}

// ---------------------------------------------------------------------------
// Kernel C: stage-3 fused pass. Per (b,n):
//   sim2_s = <g_s, x_col> + h_s; softmax over s; out_c = sum_s st[s][c]*a2[s] + x_c
// ---------------------------------------------------------------------------
__global__ __launch_bounds__(256) void k_feat(
    const float* __restrict__ x,
    const float* __restrict__ st_g, const float* __restrict__ g_g,
    const float* __restrict__ h_g,
    float* __restrict__ out)
{
    __shared__ float stS[SS*CC];       // 2 KB
    __shared__ float gS [SS*CC];       // 2 KB
    __shared__ float hS [SS];

    const int tid = threadIdx.x;
    const int b  = blockIdx.x >> 9;               // 512 blocks per batch
    const int n  = ((blockIdx.x & 511) << 8) + tid;

    for (int i = tid; i < SS*CC; i += 256) {
        stS[i] = st_g[b*SS*CC + i];
        gS[i]  = g_g [b*SS*CC + i];
    }
    if (tid < SS) hS[tid] = h_g[b*SS + tid];
    __syncthreads();

    const float* xb = x + (size_t)b * CC * NN + n;
    float xc[CC];
    #pragma unroll
    for (int c = 0; c < CC; ++c) xc[c] = xb[(size_t)c * NN];

    // sim2 = g . x + h
    float a[SS];
    #pragma unroll
    for (int s = 0; s < SS; ++s) a[s] = hS[s];
    #pragma unroll
    for (int c4 = 0; c4 < CC/4; ++c4) {
        #pragma unroll
        for (int s = 0; s < SS; ++s) {
            float4 g4 = *(const float4*)(&gS[s*CC + c4*4]);
            a[s] += g4.x*xc[c4*4+0] + g4.y*xc[c4*4+1]
                  + g4.z*xc[c4*4+2] + g4.w*xc[c4*4+3];
        }
    }

    // softmax over slots
    float m = a[0];
    #pragma unroll
    for (int s = 1; s < SS; ++s) m = fmaxf(m, a[s]);
    float l = 0.f;
    #pragma unroll
    for (int s = 0; s < SS; ++s) { a[s] = __expf(a[s] - m); l += a[s]; }
    const float inv = 1.f / l;

    // out = st^T @ a2 + x
    float* ob = out + (size_t)b * CC * NN + n;
    #pragma unroll
    for (int c4 = 0; c4 < CC/4; ++c4) {
        float o0 = 0.f, o1 = 0.f, o2 = 0.f, o3 = 0.f;
        #pragma unroll
        for (int s = 0; s < SS; ++s) {
            float4 s4 = *(const float4*)(&stS[s*CC + c4*4]);
            o0 += s4.x * a[s]; o1 += s4.y * a[s];
            o2 += s4.z * a[s]; o3 += s4.w * a[s];
        }
        ob[(size_t)(c4*4+0) * NN] = o0 * inv + xc[c4*4+0];
        ob[(size_t)(c4*4+1) * NN] = o1 * inv + xc[c4*4+1];
        ob[(size_t)(c4*4+2) * NN] = o2 * inv + xc[c4*4+2];
        ob[(size_t)(c4*4+3) * NN] = o3 * inv + xc[c4*4+3];
    }
}

// ---------------------------------------------------------------------------
extern "C" void kernel_launch(void* const* d_in, const int* in_sizes, int n_in,
                              void* d_out, int out_size, void* d_ws, size_t ws_size,
                              hipStream_t stream) {
    const float* x         = (const float*)d_in[0];
    const float* slot_init = (const float*)d_in[1];
    const float* spw       = (const float*)d_in[2];
    const float* spb       = (const float*)d_in[3];
    const float* lng       = (const float*)d_in[4];
    const float* lnb       = (const float*)d_in[5];
    const float* ipw       = (const float*)d_in[6];
    const float* ipb       = (const float*)d_in[7];
    const float* opw       = (const float*)d_in[8];
    const float* opb       = (const float*)d_in[9];
    const float* fw        = (const float*)d_in[10];
    const float* fb        = (const float*)d_in[11];
    const float* s2fw      = (const float*)d_in[12];
    const float* s2fb      = (const float*)d_in[13];
    float* out = (float*)d_out;

    // workspace layout (floats)
    float* w         = (float*)d_ws;
    float* U_part    = w;                       // 4*128*8*64 = 262144
    float* sume_part = w + 262144;              // 4096
    float* st_out    = w + 266240;              // 2048
    float* g_out     = w + 268288;              // 2048
    float* h_out     = w + 270336;              // 32

    k_slots_attn<<<BB * BPB, 256, 0, stream>>>(x, slot_init, U_part, sume_part);
    k_slots_small<<<1, 256, 0, stream>>>(U_part, sume_part, spw, spb, lng, lnb,
                                         ipw, ipb, opw, opb, s2fw, s2fb,
                                         fw, fb, st_out, g_out, h_out);
    k_feat<<<BB * (NN/256), 256, 0, stream>>>(x, st_out, g_out, h_out, out);
}

// Round 4
// 139.824 us; speedup vs baseline: 2.2197x; 1.1007x over previous
//
#include <hip/hip_runtime.h>
#include <hip/hip_bf16.h>

// Problem constants
#define BB   4
#define CC   64
#define SS   8
#define NN   (32*64*64)   // 131072
#define NH_  4
#define HD_  16
#define TN   256          // n-tile for stage-1 kernel
#define BPB  128          // blocks per batch in stage-1 kernel

// ---------------------------------------------------------------------------
// Kernel A: stage-1 pass over x. (unchanged)
// Per (b,n): e_s = exp(<sn_s, x/||x||>)  (sim in [-1,1] -> drop max-subtract)
// Per-block partials: U[s][c] = sum_n x[c,n]*e_s[n], L[s] = sum_n e_s[n]
// ---------------------------------------------------------------------------
__global__ __launch_bounds__(256) void k_slots_attn(
    const float* __restrict__ x, const float* __restrict__ slot_init,
    float* __restrict__ U_part, float* __restrict__ sume_part)
{
    __shared__ float xt[CC * TN];      // 64 KB, swizzled 16B slots
    __shared__ float et[SS * TN];      // 8 KB
    __shared__ float snT[SS * CC];     // 2 KB, [s][c]
    __shared__ float snorm[SS];

    const int tid = threadIdx.x;
    const int b   = blockIdx.x / BPB;
    const int blk = blockIdx.x % BPB;

    if (tid < SS) {
        float ss = 0.f;
        for (int c = 0; c < CC; ++c) { float v = slot_init[c*SS + tid]; ss += v*v; }
        snorm[tid] = fmaxf(sqrtf(ss), 1e-12f);
    }
    __syncthreads();
    if (tid < CC) {
        for (int s = 0; s < SS; ++s) snT[s*CC + tid] = slot_init[tid*SS + s] / snorm[s];
    }
    __syncthreads();

    const int s_own = tid >> 5;
    const int c0    = tid & 31;
    const int c1    = c0 + 32;
    float acc0 = 0.f, acc1 = 0.f, accS = 0.f;

    const float* xb = x + (size_t)b * CC * NN;
    const int ntiles = NN / TN;        // 512
    const int wrow = tid >> 6;
    const int j    = tid & 63;

    for (int t = blk; t < ntiles; t += BPB) {
        const int n0 = t * TN;

        #pragma unroll
        for (int k = 0; k < 16; ++k) {
            const int c = k*4 + wrow;
            float4 v = *(const float4*)(xb + (size_t)c * NN + n0 + j*4);
            const int slot = c*64 + (j ^ (c & 7));
            *(float4*)(&xt[slot*4]) = v;
        }
        __syncthreads();

        {
            float ss = 0.f;
            float a[SS];
            #pragma unroll
            for (int s = 0; s < SS; ++s) a[s] = 0.f;
            #pragma unroll
            for (int c4 = 0; c4 < 16; ++c4) {
                float xv[4];
                #pragma unroll
                for (int jj = 0; jj < 4; ++jj) {
                    const int c = c4*4 + jj;
                    xv[jj] = xt[c*TN + (tid ^ ((c & 7) << 2))];
                    ss += xv[jj] * xv[jj];
                }
                #pragma unroll
                for (int s = 0; s < SS; ++s) {
                    float4 g4 = *(const float4*)(&snT[s*CC + c4*4]);
                    a[s] += g4.x*xv[0] + g4.y*xv[1] + g4.z*xv[2] + g4.w*xv[3];
                }
            }
            const float invn = 1.f / fmaxf(sqrtf(ss), 1e-12f);
            #pragma unroll
            for (int s = 0; s < SS; ++s) et[s*TN + tid] = __expf(a[s] * invn);
        }
        __syncthreads();

        #pragma unroll 4
        for (int np4 = 0; np4 < TN/4; ++np4) {
            const float4 e4 = *(const float4*)(&et[s_own*TN + np4*4]);
            const float4 xa = *(const float4*)(&xt[(c0*64 + (np4 ^ (c0 & 7))) * 4]);
            const float4 xc = *(const float4*)(&xt[(c1*64 + (np4 ^ (c1 & 7))) * 4]);
            acc0 += e4.x*xa.x + e4.y*xa.y + e4.z*xa.z + e4.w*xa.w;
            acc1 += e4.x*xc.x + e4.y*xc.y + e4.z*xc.z + e4.w*xc.w;
            accS += e4.x + e4.y + e4.z + e4.w;
        }
        __syncthreads();
    }

    size_t base = (((size_t)b * BPB + blk) * SS + s_own) * CC;
    U_part[base + c0] = acc0;
    U_part[base + c1] = acc1;
    if (c0 == 0)
        sume_part[((size_t)b * BPB + blk) * SS + s_own] = accS;
}

// ---------------------------------------------------------------------------
// Kernel P: precompute slot-independent folds of the feature path.
//   M[cp][c] = sum_o s2fw[o][cp] * fw[o][c]
//   g0[c]    = sum_o s2fb[o]     * fw[o][c]
//   hv[cp]   = sum_o s2fw[o][cp] * fb[o]
//   h0       = sum_o s2fb[o]     * fb[o]
// Then g[bs] = st[bs]@M + g0, h[bs] = st[bs].hv + h0 (done in kernel B).
// ---------------------------------------------------------------------------
__global__ __launch_bounds__(256) void k_precomp(
    const float* __restrict__ s2fw, const float* __restrict__ s2fb,
    const float* __restrict__ fw, const float* __restrict__ fb,
    float* __restrict__ M, float* __restrict__ g0v,
    float* __restrict__ hv, float* __restrict__ h0)
{
    const int tid = threadIdx.x;
    if (blockIdx.x < 16) {
        const int cp = blockIdx.x*4 + (tid >> 6);
        const int c  = tid & 63;
        float acc = 0.f;
        #pragma unroll 8
        for (int o = 0; o < CC; ++o)
            acc += s2fw[o*CC + cp] * fw[o*CC + c];
        M[cp*CC + c] = acc;
    } else {
        if (tid < 64) {
            float acc = 0.f;
            #pragma unroll 8
            for (int o = 0; o < CC; ++o) acc += s2fb[o] * fw[o*CC + tid];
            g0v[tid] = acc;
        } else if (tid < 128) {
            const int cp = tid - 64;
            float acc = 0.f;
            #pragma unroll 8
            for (int o = 0; o < CC; ++o) acc += s2fw[o*CC + cp] * fb[o];
            hv[cp] = acc;
        } else if (tid == 128) {
            float acc = 0.f;
            for (int o = 0; o < CC; ++o) acc += s2fb[o] * fb[o];
            *h0 = acc;
        }
    }
}

// ---------------------------------------------------------------------------
// Kernel R: parallel reduce of partials -> upd[b,s,c] = U/L directly.
// One block per (b,s); threads (c, kchunk); all loads independent+coalesced.
// ---------------------------------------------------------------------------
__global__ __launch_bounds__(256) void k_reduce2(
    const float* __restrict__ U_part, const float* __restrict__ sume_part,
    float* __restrict__ upd_g)
{
    __shared__ float part[4][64];
    __shared__ float lbuf[128];
    __shared__ float Lsh;
    const int tid = threadIdx.x;
    const int b = blockIdx.x >> 3, s = blockIdx.x & 7;
    const int c = tid & 63, kc = tid >> 6;

    float lv = 0.f;
    if (tid < 128) lv = sume_part[(size_t)(b*BPB + tid)*SS + s];

    float acc = 0.f;
    const float* base = U_part + ((size_t)(b*BPB + kc*32)*SS + s)*CC + c;
    #pragma unroll 8
    for (int k = 0; k < 32; ++k)
        acc += base[(size_t)k * SS * CC];
    part[kc][c] = acc;
    if (tid < 128) lbuf[tid] = lv;
    __syncthreads();

    if (tid < 64) {
        float v = lbuf[tid] + lbuf[tid + 64];
        v += __shfl_xor(v, 1); v += __shfl_xor(v, 2); v += __shfl_xor(v, 4);
        v += __shfl_xor(v, 8); v += __shfl_xor(v, 16); v += __shfl_xor(v, 32);
        if (tid == 0) Lsh = v;
    }
    __syncthreads();

    if (tid < 64) {
        float u = part[0][c] + part[1][c] + part[2][c] + part[3][c];
        upd_g[((size_t)b*SS + s)*CC + c] = u / Lsh;
    }
}

// ---------------------------------------------------------------------------
// Kernel B: slot pipeline. 4 blocks (one per batch), 256 threads.
// Thread (c = tid&63) owns weight row c in registers; quad = tid>>6 owns
// 2 slot rows. Inputs read as wave-uniform LDS broadcasts. Phases:
// P1 slot_proj -> P2 LN -> P3 qkv -> P4 MHSA(32 thr) -> P5 out_proj+res ->
// P6 g = st@M + g0 (+ st_out, h_out).
// ---------------------------------------------------------------------------
__global__ __launch_bounds__(256) void k_slots_small(
    const float* __restrict__ upd_g,
    const float* __restrict__ spw, const float* __restrict__ spb,
    const float* __restrict__ lng, const float* __restrict__ lnb,
    const float* __restrict__ ipw, const float* __restrict__ ipb,
    const float* __restrict__ opw, const float* __restrict__ opb,
    const float* __restrict__ M, const float* __restrict__ g0v,
    const float* __restrict__ hv, const float* __restrict__ h0,
    float* __restrict__ st_out, float* __restrict__ g_out, float* __restrict__ h_out)
{
    __shared__ float upd[SS*CC];       // 2 KB
    __shared__ float st [SS*CC];
    __shared__ float snb[SS*CC];
    __shared__ float qkv[SS*3*CC];     // 6 KB
    __shared__ float ot [SS*CC];

    const int tid  = threadIdx.x;
    const int b    = blockIdx.x;
    const int c    = tid & 63;
    const int quad = tid >> 6;
    const int r0 = quad*2, r1 = r0 + 1;
    float wreg[CC];

    // ---- phase 0: prefetch spw row + load upd rows ----
    #pragma unroll
    for (int i = 0; i < 16; ++i)
        *(float4*)&wreg[i*4] = *(const float4*)(spw + c*CC + i*4);
    upd[r0*CC + c] = upd_g[(b*SS + r0)*CC + c];
    upd[r1*CC + c] = upd_g[(b*SS + r1)*CC + c];
    __syncthreads();

    // ---- P1: slot_proj ----
    {
        const float bias = spb[c];
        float a0 = bias, a1 = bias;
        #pragma unroll
        for (int i = 0; i < 16; ++i) {
            float4 u0 = *(const float4*)&upd[r0*CC + i*4];
            float4 u1 = *(const float4*)&upd[r1*CC + i*4];
            a0 += u0.x*wreg[i*4+0] + u0.y*wreg[i*4+1] + u0.z*wreg[i*4+2] + u0.w*wreg[i*4+3];
            a1 += u1.x*wreg[i*4+0] + u1.y*wreg[i*4+1] + u1.z*wreg[i*4+2] + u1.w*wreg[i*4+3];
        }
        st[r0*CC + c] = a0;
        st[r1*CC + c] = a1;
    }
    __syncthreads();

    // ---- P2: LayerNorm (32 threads per row) ----
    {
        const int row = tid >> 5, l = tid & 31;
        float v0 = st[row*CC + l], v1 = st[row*CC + l + 32];
        float sum = v0 + v1;
        sum += __shfl_xor(sum, 1); sum += __shfl_xor(sum, 2); sum += __shfl_xor(sum, 4);
        sum += __shfl_xor(sum, 8); sum += __shfl_xor(sum, 16);
        const float mu = sum * (1.f/64.f);
        const float d0 = v0 - mu, d1 = v1 - mu;
        float vs = d0*d0 + d1*d1;
        vs += __shfl_xor(vs, 1); vs += __shfl_xor(vs, 2); vs += __shfl_xor(vs, 4);
        vs += __shfl_xor(vs, 8); vs += __shfl_xor(vs, 16);
        const float rstd = rsqrtf(vs * (1.f/64.f) + 1e-5f);
        snb[row*CC + l]      = d0 * rstd * lng[l]      + lnb[l];
        snb[row*CC + l + 32] = d1 * rstd * lng[l + 32] + lnb[l + 32];
    }
    __syncthreads();

    // ---- P3: qkv = snb @ in_proj_w^T + in_proj_b ----
    for (int m = 0; m < 3; ++m) {
        #pragma unroll
        for (int i = 0; i < 16; ++i)
            *(float4*)&wreg[i*4] = *(const float4*)(ipw + (size_t)(m*CC + c)*CC + i*4);
        const float bias = ipb[m*CC + c];
        float a0 = bias, a1 = bias;
        #pragma unroll
        for (int i = 0; i < 16; ++i) {
            float4 u0 = *(const float4*)&snb[r0*CC + i*4];
            float4 u1 = *(const float4*)&snb[r1*CC + i*4];
            a0 += u0.x*wreg[i*4+0] + u0.y*wreg[i*4+1] + u0.z*wreg[i*4+2] + u0.w*wreg[i*4+3];
            a1 += u1.x*wreg[i*4+0] + u1.y*wreg[i*4+1] + u1.z*wreg[i*4+2] + u1.w*wreg[i*4+3];
        }
        qkv[r0*3*CC + m*CC + c] = a0;
        qkv[r1*3*CC + m*CC + c] = a1;
    }
    __syncthreads();

    // ---- P4: MHSA, 32 threads = (h,q) ----
    if (tid < NH_*SS) {
        const int h = tid >> 3, q = tid & 7;
        float qreg[HD_];
        #pragma unroll
        for (int i = 0; i < 4; ++i)
            *(float4*)&qreg[i*4] = *(const float4*)&qkv[q*3*CC + h*HD_ + i*4];
        float srow[SS];
        float mx = -1e30f;
        #pragma unroll
        for (int k = 0; k < SS; ++k) {
            float acc = 0.f;
            #pragma unroll
            for (int d = 0; d < HD_; ++d)
                acc += qreg[d] * qkv[k*3*CC + CC + h*HD_ + d];
            srow[k] = acc * 0.25f;     // 1/sqrt(16)
            mx = fmaxf(mx, srow[k]);
        }
        float l = 0.f;
        #pragma unroll
        for (int k = 0; k < SS; ++k) { srow[k] = __expf(srow[k] - mx); l += srow[k]; }
        const float inv = 1.f / l;
        float oreg[HD_];
        #pragma unroll
        for (int d = 0; d < HD_; ++d) oreg[d] = 0.f;
        #pragma unroll
        for (int k = 0; k < SS; ++k) {
            #pragma unroll
            for (int d = 0; d < HD_; ++d)
                oreg[d] += srow[k] * qkv[k*3*CC + 2*CC + h*HD_ + d];
        }
        #pragma unroll
        for (int d = 0; d < HD_; ++d)
            ot[q*CC + h*HD_ + d] = oreg[d] * inv;
    }
    __syncthreads();

    // ---- P5: out_proj + residual ----
    #pragma unroll
    for (int i = 0; i < 16; ++i)
        *(float4*)&wreg[i*4] = *(const float4*)(opw + c*CC + i*4);
    {
        const float bias = opb[c];
        float a0 = bias, a1 = bias;
        #pragma unroll
        for (int i = 0; i < 16; ++i) {
            float4 u0 = *(const float4*)&ot[r0*CC + i*4];
            float4 u1 = *(const float4*)&ot[r1*CC + i*4];
            a0 += u0.x*wreg[i*4+0] + u0.y*wreg[i*4+1] + u0.z*wreg[i*4+2] + u0.w*wreg[i*4+3];
            a1 += u1.x*wreg[i*4+0] + u1.y*wreg[i*4+1] + u1.z*wreg[i*4+2] + u1.w*wreg[i*4+3];
        }
        st[r0*CC + c] += a0;
        st[r1*CC + c] += a1;
    }
    __syncthreads();

    // ---- P6: g = st @ M + g0 ; emit st ; h = st.hv + h0 ----
    #pragma unroll 8
    for (int cp = 0; cp < CC; ++cp) wreg[cp] = M[cp*CC + c];   // column c, coalesced
    {
        const float g0 = g0v[c];
        float a0 = g0, a1 = g0;
        #pragma unroll
        for (int i = 0; i < 16; ++i) {
            float4 s0 = *(const float4*)&st[r0*CC + i*4];
            float4 s1 = *(const float4*)&st[r1*CC + i*4];
            a0 += s0.x*wreg[i*4+0] + s0.y*wreg[i*4+1] + s0.z*wreg[i*4+2] + s0.w*wreg[i*4+3];
            a1 += s1.x*wreg[i*4+0] + s1.y*wreg[i*4+1] + s1.z*wreg[i*4+2] + s1.w*wreg[i*4+3];
        }
        g_out[(b*SS + r0)*CC + c] = a0;
        g_out[(b*SS + r1)*CC + c] = a1;
        st_out[(b*SS + r0)*CC + c] = st[r0*CC + c];
        st_out[(b*SS + r1)*CC + c] = st[r1*CC + c];
    }
    {
        const int row = tid >> 5, l = tid & 31;
        float pv = st[row*CC + l]*hv[l] + st[row*CC + l + 32]*hv[l + 32];
        pv += __shfl_xor(pv, 1); pv += __shfl_xor(pv, 2); pv += __shfl_xor(pv, 4);
        pv += __shfl_xor(pv, 8); pv += __shfl_xor(pv, 16);
        if (l == 0) h_out[b*SS + row] = pv + *h0;
    }
}

// ---------------------------------------------------------------------------
// Kernel C: stage-3 fused pass. (unchanged)
// ---------------------------------------------------------------------------
__global__ __launch_bounds__(256) void k_feat(
    const float* __restrict__ x,
    const float* __restrict__ st_g, const float* __restrict__ g_g,
    const float* __restrict__ h_g,
    float* __restrict__ out)
{
    __shared__ float stS[SS*CC];
    __shared__ float gS [SS*CC];
    __shared__ float hS [SS];

    const int tid = threadIdx.x;
    const int b  = blockIdx.x >> 9;
    const int n  = ((blockIdx.x & 511) << 8) + tid;

    for (int i = tid; i < SS*CC; i += 256) {
        stS[i] = st_g[b*SS*CC + i];
        gS[i]  = g_g [b*SS*CC + i];
    }
    if (tid < SS) hS[tid] = h_g[b*SS + tid];
    __syncthreads();

    const float* xb = x + (size_t)b * CC * NN + n;
    float xc[CC];
    #pragma unroll
    for (int c = 0; c < CC; ++c) xc[c] = xb[(size_t)c * NN];

    float a[SS];
    #pragma unroll
    for (int s = 0; s < SS; ++s) a[s] = hS[s];
    #pragma unroll
    for (int c4 = 0; c4 < CC/4; ++c4) {
        #pragma unroll
        for (int s = 0; s < SS; ++s) {
            float4 g4 = *(const float4*)(&gS[s*CC + c4*4]);
            a[s] += g4.x*xc[c4*4+0] + g4.y*xc[c4*4+1]
                  + g4.z*xc[c4*4+2] + g4.w*xc[c4*4+3];
        }
    }

    float m = a[0];
    #pragma unroll
    for (int s = 1; s < SS; ++s) m = fmaxf(m, a[s]);
    float l = 0.f;
    #pragma unroll
    for (int s = 0; s < SS; ++s) { a[s] = __expf(a[s] - m); l += a[s]; }
    const float inv = 1.f / l;

    float* ob = out + (size_t)b * CC * NN + n;
    #pragma unroll
    for (int c4 = 0; c4 < CC/4; ++c4) {
        float o0 = 0.f, o1 = 0.f, o2 = 0.f, o3 = 0.f;
        #pragma unroll
        for (int s = 0; s < SS; ++s) {
            float4 s4 = *(const float4*)(&stS[s*CC + c4*4]);
            o0 += s4.x * a[s]; o1 += s4.y * a[s];
            o2 += s4.z * a[s]; o3 += s4.w * a[s];
        }
        ob[(size_t)(c4*4+0) * NN] = o0 * inv + xc[c4*4+0];
        ob[(size_t)(c4*4+1) * NN] = o1 * inv + xc[c4*4+1];
        ob[(size_t)(c4*4+2) * NN] = o2 * inv + xc[c4*4+2];
        ob[(size_t)(c4*4+3) * NN] = o3 * inv + xc[c4*4+3];
    }
}

// ---------------------------------------------------------------------------
extern "C" void kernel_launch(void* const* d_in, const int* in_sizes, int n_in,
                              void* d_out, int out_size, void* d_ws, size_t ws_size,
                              hipStream_t stream) {
    const float* x         = (const float*)d_in[0];
    const float* slot_init = (const float*)d_in[1];
    const float* spw       = (const float*)d_in[2];
    const float* spb       = (const float*)d_in[3];
    const float* lng       = (const float*)d_in[4];
    const float* lnb       = (const float*)d_in[5];
    const float* ipw       = (const float*)d_in[6];
    const float* ipb       = (const float*)d_in[7];
    const float* opw       = (const float*)d_in[8];
    const float* opb       = (const float*)d_in[9];
    const float* fw        = (const float*)d_in[10];
    const float* fb        = (const float*)d_in[11];
    const float* s2fw      = (const float*)d_in[12];
    const float* s2fb      = (const float*)d_in[13];
    float* out = (float*)d_out;

    // workspace layout (floats)
    float* w         = (float*)d_ws;
    float* U_part    = w;                       // 262144
    float* sume_part = w + 262144;              // 4096
    float* upd_g     = w + 266240;              // 2048
    float* Mm        = w + 268288;              // 4096
    float* g0v       = w + 272384;              // 64
    float* hv        = w + 272448;              // 64
    float* h0        = w + 272512;              // 64 (1 used)
    float* st_out    = w + 272576;              // 2048
    float* g_out     = w + 274624;              // 2048
    float* h_out     = w + 276672;              // 32

    k_precomp<<<17, 256, 0, stream>>>(s2fw, s2fb, fw, fb, Mm, g0v, hv, h0);
    k_slots_attn<<<BB * BPB, 256, 0, stream>>>(x, slot_init, U_part, sume_part);
    k_reduce2<<<BB * SS, 256, 0, stream>>>(U_part, sume_part, upd_g);
    k_slots_small<<<BB, 256, 0, stream>>>(upd_g, spw, spb, lng, lnb,
                                          ipw, ipb, opw, opb, Mm, g0v, hv, h0,
                                          st_out, g_out, h_out);
    k_feat<<<BB * (NN/256), 256, 0, stream>>>(x, st_out, g_out, h_out, out);
}